// Round 1
// baseline (517.064 us; speedup 1.0000x reference)
//
#include <hip/hip_runtime.h>

#define IMG_W 8192
#define IMG_H 8192
#define KS 15
#define RAD 7
#define TW 64
#define TH 64
#define BLOCK 256
#define SIN_W (TW + 2*RAD)      // 78
#define SIN_H (TH + 2*RAD)      // 78
#define SIN_STRIDE 80           // pad to break power-of-2 strides
#define MID_STRIDE TW           // 64

__device__ __forceinline__ int reflect_idx(int p, int n) {
    if (p < 0) p = -p;
    if (p >= n) p = 2 * n - 2 - p;
    return p;
}

__global__ __launch_bounds__(BLOCK)
void gauss15_fused(const float* __restrict__ in,
                   const float* __restrict__ k2d,
                   float* __restrict__ out) {
    __shared__ float s_in[SIN_H * SIN_STRIDE];
    __shared__ float s_mid[SIN_H * MID_STRIDE];
    __shared__ float s_kx[KS];
    __shared__ float s_ky[KS];

    const int t = threadIdx.x;
    const int col0 = blockIdx.x * TW;
    const int row0 = blockIdx.y * TH;

    // Recover separable 1D kernels: K2 = outer(ky, kx), each 1D sums to 1,
    // so row-sums give ky and col-sums give kx exactly.
    if (t < KS) {
        float sx = 0.f, sy = 0.f;
        #pragma unroll
        for (int i = 0; i < KS; i++) {
            sx += k2d[i * KS + t];   // column t sum -> kx[t]
            sy += k2d[t * KS + i];   // row t sum    -> ky[t]
        }
        s_kx[t] = sx;
        s_ky[t] = sy;
    }

    // ---- Stage A: global -> LDS tile load with reflect padding ----
    for (int idx = t; idx < SIN_H * SIN_W; idx += BLOCK) {
        int r = idx / SIN_W;
        int c = idx - r * SIN_W;
        int gr = reflect_idx(row0 - RAD + r, IMG_H);
        int gc = reflect_idx(col0 - RAD + c, IMG_W);
        s_in[r * SIN_STRIDE + c] = in[gr * IMG_W + gc];
    }
    __syncthreads();

    float kx[KS], ky[KS];
    #pragma unroll
    for (int i = 0; i < KS; i++) { kx[i] = s_kx[i]; ky[i] = s_ky[i]; }

    // ---- Stage B: horizontal conv, LDS -> LDS mid. 4 outputs per task ----
    // Tasks: SIN_H rows x (TW/4) col-groups = 78*16 = 1248
    for (int idx = t; idx < SIN_H * (TW / 4); idx += BLOCK) {
        int r = idx >> 4;           // / (TW/4)
        int cg = idx & 15;
        const float* rowp = &s_in[r * SIN_STRIDE + cg * 4];
        float f[20];
        *(float4*)(f + 0)  = *(const float4*)(rowp + 0);
        *(float4*)(f + 4)  = *(const float4*)(rowp + 4);
        *(float4*)(f + 8)  = *(const float4*)(rowp + 8);
        *(float4*)(f + 12) = *(const float4*)(rowp + 12);
        *(float4*)(f + 16) = *(const float4*)(rowp + 16);
        float a0 = 0.f, a1 = 0.f, a2 = 0.f, a3 = 0.f;
        #pragma unroll
        for (int j = 0; j < KS; j++) {
            float w = kx[j];
            a0 += f[j + 0] * w;
            a1 += f[j + 1] * w;
            a2 += f[j + 2] * w;
            a3 += f[j + 3] * w;
        }
        *(float4*)&s_mid[r * MID_STRIDE + cg * 4] = make_float4(a0, a1, a2, a3);
    }
    __syncthreads();

    // ---- Stage C: vertical conv from mid, 4 cols x 4 rows per thread ----
    const int cg = t & 15;          // 16 col groups of 4
    const int rg = t >> 4;          // 16 row groups of 4
    const int c = cg * 4;
    const int r0 = rg * 4;

    float4 acc[4];
    #pragma unroll
    for (int q = 0; q < 4; q++) acc[q] = make_float4(0.f, 0.f, 0.f, 0.f);

    #pragma unroll
    for (int i = 0; i < KS + 3; i++) {   // 18 mid rows feed 4 output rows
        float4 v = *(const float4*)&s_mid[(r0 + i) * MID_STRIDE + c];
        #pragma unroll
        for (int q = 0; q < 4; q++) {
            int j = i - q;
            if (j >= 0 && j < KS) {
                float w = ky[j];
                acc[q].x += v.x * w;
                acc[q].y += v.y * w;
                acc[q].z += v.z * w;
                acc[q].w += v.w * w;
            }
        }
    }

    #pragma unroll
    for (int q = 0; q < 4; q++) {
        *(float4*)&out[(size_t)(row0 + r0 + q) * IMG_W + col0 + c] = acc[q];
    }
}

extern "C" void kernel_launch(void* const* d_in, const int* in_sizes, int n_in,
                              void* d_out, int out_size, void* d_ws, size_t ws_size,
                              hipStream_t stream) {
    const float* img = (const float*)d_in[0];
    const float* k2d = (const float*)d_in[1];
    // d_in[2] is stride (==1 per setup_inputs); output size confirms stride 1.
    float* out = (float*)d_out;

    dim3 grid(IMG_W / TW, IMG_H / TH);
    gauss15_fused<<<grid, BLOCK, 0, stream>>>(img, k2d, out);
}